// Round 1
// baseline (175.180 us; speedup 1.0000x reference)
//
#include <hip/hip_runtime.h>

// Problem constants
#define NN 8192
#define EE 65536
#define IN_C 64
#define L1C 48
#define L2C 32
#define OUT_C 16
#define EF 8

// T1 columns: 8 weight slices (8*48) + bias-matrix (48) + root1 (48) = 480
#define T1_COLS 480
// T2 columns: 8 weight slices (8*32) + bias-matrix (32) + root2 (32) = 320
#define T2_COLS 320

// ---------------------------------------------------------------------------
// k_T1: T1[n][c] = sum_i x[n][i] * Wcol[c][i], Wcol stride 48.
//   c in [0,384): f=c/48, W = nn1_w[f*3072 + i*48 + o]
//   c in [384,432): nn1_b[i*48+o]   (bias reshaped (64,48))
//   c in [432,480): root1[i*48+o]
// ---------------------------------------------------------------------------
__global__ __launch_bounds__(256) void k_T1(const float* __restrict__ x,
                                            const float* __restrict__ w,
                                            const float* __restrict__ b,
                                            const float* __restrict__ root,
                                            float* __restrict__ T1) {
    __shared__ float xsT[64 * 16];  // [i][n]
    const int n0 = blockIdx.x * 16;
    for (int t = threadIdx.x; t < 16 * 64; t += 256) {
        int n = t >> 6, i = t & 63;
        xsT[i * 16 + n] = x[(n0 + n) * 64 + i];
    }
    __syncthreads();
    for (int c = threadIdx.x; c < T1_COLS; c += 256) {
        int f = c / 48, o = c - f * 48;
        const float* wp;
        if (f < 8)      wp = w + f * 3072 + o;
        else if (f == 8) wp = b + o;
        else             wp = root + o;
        float acc[16];
#pragma unroll
        for (int n = 0; n < 16; n++) acc[n] = 0.f;
#pragma unroll 16
        for (int i = 0; i < 64; i++) {
            float wv = wp[i * 48];
            const float* xr = &xsT[i * 16];
#pragma unroll
            for (int n = 0; n < 16; n++) acc[n] += xr[n] * wv;
        }
#pragma unroll
        for (int n = 0; n < 16; n++) T1[(size_t)(n0 + n) * T1_COLS + c] = acc[n];
    }
}

// k_T2: same but K=48, col stride 32, inputs h1.
__global__ __launch_bounds__(256) void k_T2(const float* __restrict__ h1,
                                            const float* __restrict__ w,
                                            const float* __restrict__ b,
                                            const float* __restrict__ root,
                                            float* __restrict__ T2) {
    __shared__ float xsT[48 * 16];
    const int n0 = blockIdx.x * 16;
    for (int t = threadIdx.x; t < 16 * 48; t += 256) {
        int n = t / 48, i = t - n * 48;
        xsT[i * 16 + n] = h1[(n0 + n) * 48 + i];
    }
    __syncthreads();
    for (int c = threadIdx.x; c < T2_COLS; c += 256) {
        int f = c >> 5, o = c & 31;
        const float* wp;
        if (f < 8)      wp = w + f * 1536 + o;
        else if (f == 8) wp = b + o;
        else             wp = root + o;
        float acc[16];
#pragma unroll
        for (int n = 0; n < 16; n++) acc[n] = 0.f;
#pragma unroll 16
        for (int i = 0; i < 48; i++) {
            float wv = wp[i * 32];
            const float* xr = &xsT[i * 16];
#pragma unroll
            for (int n = 0; n < 16; n++) acc[n] += xr[n] * wv;
        }
#pragma unroll
        for (int n = 0; n < 16; n++) T2[(size_t)(n0 + n) * T2_COLS + c] = acc[n];
    }
}

__global__ __launch_bounds__(256) void k_zero(float* __restrict__ p, int n4) {
    int i = blockIdx.x * 256 + threadIdx.x;
    if (i < n4) ((float4*)p)[i] = make_float4(0.f, 0.f, 0.f, 0.f);
}

// ---------------------------------------------------------------------------
// CSR build (counting sort by dst). ~131K tiny int atomics total, replaces
// ~7.3M f32 atomics in the aggregation stages.
// ---------------------------------------------------------------------------
__global__ __launch_bounds__(256) void k_count(const int* __restrict__ ei,
                                               int* __restrict__ cnt) {
    int e = blockIdx.x * 256 + threadIdx.x;
    if (e < EE) atomicAdd(&cnt[ei[EE + e]], 1);
}

// Single block: exclusive scan of cnt[8192] -> rowstart[8193]; cursor=rowstart.
__global__ __launch_bounds__(256) void k_scan(const int* __restrict__ cnt,
                                              int* __restrict__ rowstart,
                                              int* __restrict__ cursor) {
    __shared__ int part[256];
    const int t = threadIdx.x;
    const int base = t * 32;
    int local[32];
    int sum = 0;
#pragma unroll
    for (int k = 0; k < 32; k++) { local[k] = cnt[base + k]; sum += local[k]; }
    part[t] = sum;
    __syncthreads();
    if (t == 0) {
        int run = 0;
        for (int i = 0; i < 256; i++) { int c = part[i]; part[i] = run; run += c; }
    }
    __syncthreads();
    int run = part[t];
#pragma unroll
    for (int k = 0; k < 32; k++) {
        rowstart[base + k] = run;
        cursor[base + k] = run;
        run += local[k];
    }
    if (t == 255) rowstart[8192] = run;  // == EE
}

__global__ __launch_bounds__(256) void k_scatter(const int* __restrict__ ei,
                                                 int* __restrict__ cursor,
                                                 int* __restrict__ ssrc,
                                                 int* __restrict__ seid) {
    int e = blockIdx.x * 256 + threadIdx.x;
    if (e >= EE) return;
    int d = ei[EE + e];
    int pos = atomicAdd(&cursor[d], 1);
    ssrc[pos] = ei[e];
    seid[pos] = e;
}

// ---------------------------------------------------------------------------
// k_agg1: gather form of edge1 + h1 fusion. Thread = (node n, output o<48).
//   h1[n][o] = relu( sum_{e in CSR[n]} (T1[s][384+o] + sum_f ea[e][f]*T1[s][f*48+o])
//                    + T1[n][432+o] + bias1[o] )
// No atomics, no agg1 buffer, no zeroing pass.
// ---------------------------------------------------------------------------
__global__ __launch_bounds__(256) void k_agg1(const int* __restrict__ rowstart,
                                              const int* __restrict__ ssrc,
                                              const int* __restrict__ seid,
                                              const float* __restrict__ ea,
                                              const float* __restrict__ T1,
                                              const float* __restrict__ bias1,
                                              float* __restrict__ h1) {
    int idx = blockIdx.x * 256 + threadIdx.x;
    int n = idx / 48, o = idx - n * 48;
    if (n >= NN) return;
    const int rs = rowstart[n], re = rowstart[n + 1];
    float m = 0.f;
    for (int j = rs; j < re; ++j) {
        int s = ssrc[j], eid = seid[j];
        const float* t = T1 + (size_t)s * T1_COLS + o;
        const float4* a4 = (const float4*)(ea + (size_t)eid * 8);
        float4 a0 = a4[0], a1 = a4[1];
        float acc = t[384];
        acc += a0.x * t[0 * 48];
        acc += a0.y * t[1 * 48];
        acc += a0.z * t[2 * 48];
        acc += a0.w * t[3 * 48];
        acc += a1.x * t[4 * 48];
        acc += a1.y * t[5 * 48];
        acc += a1.z * t[6 * 48];
        acc += a1.w * t[7 * 48];
        m += acc;
    }
    float v = m + T1[(size_t)n * T1_COLS + 432 + o] + bias1[o];
    h1[(size_t)n * 48 + o] = v > 0.f ? v : 0.f;
}

// ---------------------------------------------------------------------------
// k_agg2: gather form of edge2 + full k_post fusion. 8 nodes/block,
// thread = (node-sub, o<32). Computes h2, then hmu/hls matvecs, dinv and the
// self-loop-initialized output. deg comes from CSR rowstarts (no deg atomics).
// ---------------------------------------------------------------------------
__global__ __launch_bounds__(256) void k_agg2(const int* __restrict__ rowstart,
                                              const int* __restrict__ ssrc,
                                              const int* __restrict__ seid,
                                              const float* __restrict__ ea,
                                              const float* __restrict__ T2,
                                              const float* __restrict__ bias2,
                                              const float* __restrict__ mu_w,
                                              const float* __restrict__ mu_b,
                                              const float* __restrict__ ls_w,
                                              const float* __restrict__ ls_b,
                                              float* __restrict__ hmu,
                                              float* __restrict__ hls,
                                              float* __restrict__ dinv,
                                              float* __restrict__ out) {
    __shared__ float h2s[8][32];
    const int n0 = blockIdx.x * 8;
    const int lid = threadIdx.x >> 5;
    const int o = threadIdx.x & 31;
    const int n = n0 + lid;
    const int rs = rowstart[n], re = rowstart[n + 1];
    float m = 0.f;
    for (int j = rs; j < re; ++j) {
        int s = ssrc[j], eid = seid[j];
        const float* t = T2 + (size_t)s * T2_COLS + o;
        const float4* a4 = (const float4*)(ea + (size_t)eid * 8);
        float4 a0 = a4[0], a1 = a4[1];
        float acc = t[256];
        acc += a0.x * t[0 * 32];
        acc += a0.y * t[1 * 32];
        acc += a0.z * t[2 * 32];
        acc += a0.w * t[3 * 32];
        acc += a1.x * t[4 * 32];
        acc += a1.y * t[5 * 32];
        acc += a1.z * t[6 * 32];
        acc += a1.w * t[7 * 32];
        m += acc;
    }
    float v = m + T2[(size_t)n * T2_COLS + 288 + o] + bias2[o];
    h2s[lid][o] = v > 0.f ? v : 0.f;
    __syncthreads();
    const float* wm = (o < 16) ? mu_w : ls_w;
    const float* bb = (o < 16) ? mu_b : ls_b;
    const int oo = o & 15;
    float acc = 0.f;
#pragma unroll
    for (int i = 0; i < 32; i++) acc += h2s[lid][i] * wm[i * 16 + oo];
    float d = (float)(re - rs) + 1.0f;
    float di = rsqrtf(d);
    if (o == 0) dinv[n] = di;
    float init = acc / d + bb[oo];
    if (o < 16) {
        hmu[(size_t)n * 16 + oo] = acc;
        out[(size_t)n * 16 + oo] = init;
    } else {
        hls[(size_t)n * 16 + oo] = acc;
        out[(size_t)NN * 16 + (size_t)n * 16 + oo] = init;
    }
}

// ---------------------------------------------------------------------------
// k_gcn: gather form of the GCN edge scatter; plain read-modify-write of out
// (out already holds self-loop + bias from k_agg2). Thread = (d, o<16), does
// both mu and ls to reuse the index/dinv loads.
// ---------------------------------------------------------------------------
__global__ __launch_bounds__(256) void k_gcn(const int* __restrict__ rowstart,
                                             const int* __restrict__ ssrc,
                                             const float* __restrict__ hmu,
                                             const float* __restrict__ hls,
                                             const float* __restrict__ dinv,
                                             float* __restrict__ out) {
    int idx = blockIdx.x * 256 + threadIdx.x;
    int d = idx >> 4, o = idx & 15;
    if (d >= NN) return;
    const int rs = rowstart[d], re = rowstart[d + 1];
    float accm = 0.f, accl = 0.f;
    for (int j = rs; j < re; ++j) {
        int s = ssrc[j];
        float ds_ = dinv[s];
        accm += hmu[(size_t)s * 16 + o] * ds_;
        accl += hls[(size_t)s * 16 + o] * ds_;
    }
    float did = dinv[d];
    out[(size_t)d * 16 + o] += accm * did;
    out[(size_t)NN * 16 + (size_t)d * 16 + o] += accl * did;
}

extern "C" void kernel_launch(void* const* d_in, const int* in_sizes, int n_in,
                              void* d_out, int out_size, void* d_ws, size_t ws_size,
                              hipStream_t stream) {
    const float* x     = (const float*)d_in[0];
    const int*   ei    = (const int*)d_in[1];
    const float* ea    = (const float*)d_in[2];
    const float* nn1_w = (const float*)d_in[3];
    const float* nn1_b = (const float*)d_in[4];
    const float* root1 = (const float*)d_in[5];
    const float* bias1 = (const float*)d_in[6];
    const float* nn2_w = (const float*)d_in[7];
    const float* nn2_b = (const float*)d_in[8];
    const float* root2 = (const float*)d_in[9];
    const float* bias2 = (const float*)d_in[10];
    const float* mu_w  = (const float*)d_in[11];
    const float* mu_b  = (const float*)d_in[12];
    const float* ls_w  = (const float*)d_in[13];
    const float* ls_b  = (const float*)d_in[14];
    float* out = (float*)d_out;

    // Workspace layout (floats). T2 aliases T1 (T1 dead after k_agg1).
    float* W    = (float*)d_ws;
    float* T1   = W;                       // 8192*480 = 3,932,160
    float* T2   = W;                       // alias
    float* h1   = W + 3932160;             // 393,216
    float* hmu  = h1 + 393216;             // 131,072
    float* hls  = hmu + 131072;            // 131,072
    float* dinv = hls + 131072;            // 8,192
    int* cnt      = (int*)(dinv + 8192);   // 8,192
    int* rowstart = cnt + 8192;            // 8,193
    int* cursor   = rowstart + 8193;       // 8,192
    int* ssrc     = cursor + 8192;         // 65,536
    int* seid     = ssrc + 65536;          // 65,536
    // total ~19 MB

    // CSR build by dst (counting sort), then all aggregations are gathers.
    k_zero<<<dim3(8), dim3(256), 0, stream>>>((float*)cnt, 2048);  // 8192 ints
    k_count<<<dim3(EE / 256), dim3(256), 0, stream>>>(ei, cnt);
    k_T1<<<dim3(NN / 16), dim3(256), 0, stream>>>(x, nn1_w, nn1_b, root1, T1);
    k_scan<<<dim3(1), dim3(256), 0, stream>>>(cnt, rowstart, cursor);
    k_scatter<<<dim3(EE / 256), dim3(256), 0, stream>>>(ei, cursor, ssrc, seid);
    k_agg1<<<dim3((NN * 48 + 255) / 256), dim3(256), 0, stream>>>(
        rowstart, ssrc, seid, ea, T1, bias1, h1);
    k_T2<<<dim3(NN / 16), dim3(256), 0, stream>>>(h1, nn2_w, nn2_b, root2, T2);
    k_agg2<<<dim3(NN / 8), dim3(256), 0, stream>>>(
        rowstart, ssrc, seid, ea, T2, bias2, mu_w, mu_b, ls_w, ls_b,
        hmu, hls, dinv, out);
    k_gcn<<<dim3((NN * 16) / 256), dim3(256), 0, stream>>>(
        rowstart, ssrc, hmu, hls, dinv, out);
}

// Round 2
// 166.173 us; speedup vs baseline: 1.0542x; 1.0542x over previous
//
#include <hip/hip_runtime.h>

// Problem constants
#define NN 8192
#define EE 65536
#define IN_C 64
#define L1C 48
#define L2C 32
#define OUT_C 16
#define EF 8

// T1 columns: 8 weight slices (8*48) + bias-matrix (48) + root1 (48) = 480
#define T1_COLS 480
// T2 columns: 8 weight slices (8*32) + bias-matrix (32) + root2 (32) = 320
#define T2_COLS 320

// ---------------------------------------------------------------------------
// k_T1: T1[n][c] = sum_i x[n][i] * Wcol[c][i], Wcol stride 48.
// ---------------------------------------------------------------------------
__global__ __launch_bounds__(256) void k_T1(const float* __restrict__ x,
                                            const float* __restrict__ w,
                                            const float* __restrict__ b,
                                            const float* __restrict__ root,
                                            float* __restrict__ T1) {
    __shared__ float xsT[64 * 16];  // [i][n]
    const int n0 = blockIdx.x * 16;
    for (int t = threadIdx.x; t < 16 * 64; t += 256) {
        int n = t >> 6, i = t & 63;
        xsT[i * 16 + n] = x[(n0 + n) * 64 + i];
    }
    __syncthreads();
    for (int c = threadIdx.x; c < T1_COLS; c += 256) {
        int f = c / 48, o = c - f * 48;
        const float* wp;
        if (f < 8)      wp = w + f * 3072 + o;
        else if (f == 8) wp = b + o;
        else             wp = root + o;
        float acc[16];
#pragma unroll
        for (int n = 0; n < 16; n++) acc[n] = 0.f;
#pragma unroll 16
        for (int i = 0; i < 64; i++) {
            float wv = wp[i * 48];
            const float* xr = &xsT[i * 16];
#pragma unroll
            for (int n = 0; n < 16; n++) acc[n] += xr[n] * wv;
        }
#pragma unroll
        for (int n = 0; n < 16; n++) T1[(size_t)(n0 + n) * T1_COLS + c] = acc[n];
    }
}

// k_T2: same but K=48, col stride 32, inputs h1.
__global__ __launch_bounds__(256) void k_T2(const float* __restrict__ h1,
                                            const float* __restrict__ w,
                                            const float* __restrict__ b,
                                            const float* __restrict__ root,
                                            float* __restrict__ T2) {
    __shared__ float xsT[48 * 16];
    const int n0 = blockIdx.x * 16;
    for (int t = threadIdx.x; t < 16 * 48; t += 256) {
        int n = t / 48, i = t - n * 48;
        xsT[i * 16 + n] = h1[(n0 + n) * 48 + i];
    }
    __syncthreads();
    for (int c = threadIdx.x; c < T2_COLS; c += 256) {
        int f = c >> 5, o = c & 31;
        const float* wp;
        if (f < 8)      wp = w + f * 1536 + o;
        else if (f == 8) wp = b + o;
        else             wp = root + o;
        float acc[16];
#pragma unroll
        for (int n = 0; n < 16; n++) acc[n] = 0.f;
#pragma unroll 16
        for (int i = 0; i < 48; i++) {
            float wv = wp[i * 32];
            const float* xr = &xsT[i * 16];
#pragma unroll
            for (int n = 0; n < 16; n++) acc[n] += xr[n] * wv;
        }
#pragma unroll
        for (int n = 0; n < 16; n++) T2[(size_t)(n0 + n) * T2_COLS + c] = acc[n];
    }
}

__global__ __launch_bounds__(256) void k_zero(float* __restrict__ p, int n4) {
    int i = blockIdx.x * 256 + threadIdx.x;
    if (i < n4) ((float4*)p)[i] = make_float4(0.f, 0.f, 0.f, 0.f);
}

// ---------------------------------------------------------------------------
// Src-sort build (counting sort by src). Also counts dst-degree for the GCN.
// ---------------------------------------------------------------------------
__global__ __launch_bounds__(256) void k_count(const int* __restrict__ ei,
                                               int* __restrict__ cnt_src,
                                               int* __restrict__ cnt_dst) {
    int e = blockIdx.x * 256 + threadIdx.x;
    if (e < EE) {
        atomicAdd(&cnt_src[ei[e]], 1);
        atomicAdd(&cnt_dst[ei[EE + e]], 1);
    }
}

// Single block: exclusive scan of cnt_src[8192] -> cursor[8192].
__global__ __launch_bounds__(256) void k_scan(const int* __restrict__ cnt,
                                              int* __restrict__ cursor) {
    __shared__ int part[256];
    const int t = threadIdx.x;
    const int base = t * 32;
    int local[32];
    int sum = 0;
#pragma unroll
    for (int k = 0; k < 32; k++) { local[k] = cnt[base + k]; sum += local[k]; }
    part[t] = sum;
    __syncthreads();
    if (t == 0) {
        int run = 0;
        for (int i = 0; i < 256; i++) { int c = part[i]; part[i] = run; run += c; }
    }
    __syncthreads();
    int run = part[t];
#pragma unroll
    for (int k = 0; k < 32; k++) {
        cursor[base + k] = run;
        run += local[k];
    }
}

// Scatter edges into src-sorted order; copy ea alongside so later reads of the
// edge features are coalesced.
__global__ __launch_bounds__(256) void k_scatter(const int* __restrict__ ei,
                                                 const float* __restrict__ ea,
                                                 int* __restrict__ cursor,
                                                 int* __restrict__ ssrc,
                                                 int* __restrict__ sdst,
                                                 float* __restrict__ sea) {
    int e = blockIdx.x * 256 + threadIdx.x;
    if (e >= EE) return;
    int s = ei[e], d = ei[EE + e];
    int pos = atomicAdd(&cursor[s], 1);
    ssrc[pos] = s;
    sdst[pos] = d;
    const float4* a = (const float4*)(ea + (size_t)e * 8);
    float4* bp = (float4*)(sea + (size_t)pos * 8);
    bp[0] = a[0];
    bp[1] = a[1];
}

// ---------------------------------------------------------------------------
// k_edge1: scatter form, src-sorted edge order. Consecutive j share src ->
// T1 row (1.7 KB) hits per-CU L1 after first touch.
// ---------------------------------------------------------------------------
__global__ __launch_bounds__(256) void k_edge1(const int* __restrict__ ssrc,
                                               const int* __restrict__ sdst,
                                               const float* __restrict__ sea,
                                               const float* __restrict__ T1,
                                               float* __restrict__ agg1) {
    int idx = blockIdx.x * 256 + threadIdx.x;
    int j = idx / 48, o = idx - j * 48;
    if (j >= EE) return;
    int s = ssrc[j], d = sdst[j];
    const float* t = T1 + (size_t)s * T1_COLS + o;
    const float4* a4 = (const float4*)(sea + (size_t)j * 8);
    float4 a0 = a4[0], a1 = a4[1];
    float m = t[384];
    m += a0.x * t[0 * 48];
    m += a0.y * t[1 * 48];
    m += a0.z * t[2 * 48];
    m += a0.w * t[3 * 48];
    m += a1.x * t[4 * 48];
    m += a1.y * t[5 * 48];
    m += a1.z * t[6 * 48];
    m += a1.w * t[7 * 48];
    atomicAdd(agg1 + (size_t)d * 48 + o, m);
}

__global__ __launch_bounds__(256) void k_h1(const float* __restrict__ agg1,
                                            const float* __restrict__ T1,
                                            const float* __restrict__ bias1,
                                            float* __restrict__ h1) {
    int idx = blockIdx.x * 256 + threadIdx.x;
    if (idx >= NN * 48) return;
    int n = idx / 48, o = idx - n * 48;
    float v = agg1[idx] + T1[(size_t)n * T1_COLS + 432 + o] + bias1[o];
    h1[idx] = v > 0.f ? v : 0.f;
}

// k_edge2: layer-2 scatter, src-sorted (deg comes from cnt_dst now).
__global__ __launch_bounds__(256) void k_edge2(const int* __restrict__ ssrc,
                                               const int* __restrict__ sdst,
                                               const float* __restrict__ sea,
                                               const float* __restrict__ T2,
                                               float* __restrict__ agg2) {
    int idx = blockIdx.x * 256 + threadIdx.x;
    int j = idx >> 5, o = idx & 31;
    if (j >= EE) return;
    int s = ssrc[j], d = sdst[j];
    const float* t = T2 + (size_t)s * T2_COLS + o;
    const float4* a4 = (const float4*)(sea + (size_t)j * 8);
    float4 a0 = a4[0], a1 = a4[1];
    float m = t[256];
    m += a0.x * t[0 * 32];
    m += a0.y * t[1 * 32];
    m += a0.z * t[2 * 32];
    m += a0.w * t[3 * 32];
    m += a1.x * t[4 * 32];
    m += a1.y * t[5 * 32];
    m += a1.z * t[6 * 32];
    m += a1.w * t[7 * 32];
    atomicAdd(agg2 + (size_t)d * 32 + o, m);
}

// k_post: h2 = relu(agg2 + root-part + bias2); hmu = h2@mu_w; hls = h2@ls_w;
// init out with self-loop term + bias; deg from cnt_dst.
__global__ __launch_bounds__(256) void k_post(const float* __restrict__ agg2,
                                              const float* __restrict__ T2,
                                              const float* __restrict__ bias2,
                                              const float* __restrict__ mu_w,
                                              const float* __restrict__ mu_b,
                                              const float* __restrict__ ls_w,
                                              const float* __restrict__ ls_b,
                                              const int* __restrict__ cnt_dst,
                                              float* __restrict__ hmu,
                                              float* __restrict__ hls,
                                              float* __restrict__ dinv,
                                              float* __restrict__ out) {
    __shared__ float h2s[8][32];
    const int n0 = blockIdx.x * 8;
    const int lid = threadIdx.x >> 5;
    const int o = threadIdx.x & 31;
    const int n = n0 + lid;
    float v = agg2[(size_t)n * 32 + o] + T2[(size_t)n * T2_COLS + 288 + o] + bias2[o];
    v = v > 0.f ? v : 0.f;
    h2s[lid][o] = v;
    __syncthreads();
    const float* wm = (o < 16) ? mu_w : ls_w;
    const float* bb = (o < 16) ? mu_b : ls_b;
    const int oo = o & 15;
    float acc = 0.f;
#pragma unroll
    for (int i = 0; i < 32; i++) acc += h2s[lid][i] * wm[i * 16 + oo];
    float d = (float)cnt_dst[n] + 1.0f;
    float di = rsqrtf(d);
    if (o == 0) dinv[n] = di;
    float init = acc / d + bb[oo];
    if (o < 16) {
        hmu[(size_t)n * 16 + oo] = acc;
        out[(size_t)n * 16 + oo] = init;
    } else {
        hls[(size_t)n * 16 + oo] = acc;
        out[(size_t)NN * 16 + (size_t)n * 16 + oo] = init;
    }
}

// k_gcn_edge: src-sorted scatter; hmu/hls rows hit L1 across the src group.
__global__ __launch_bounds__(256) void k_gcn_edge(const int* __restrict__ ssrc,
                                                  const int* __restrict__ sdst,
                                                  const float* __restrict__ hmu,
                                                  const float* __restrict__ hls,
                                                  const float* __restrict__ dinv,
                                                  float* __restrict__ out) {
    int idx = blockIdx.x * 256 + threadIdx.x;
    int j = idx >> 4, o = idx & 15;
    if (j >= EE) return;
    int s = ssrc[j], d = sdst[j];
    float norm = dinv[s] * dinv[d];
    atomicAdd(out + (size_t)d * 16 + o, hmu[(size_t)s * 16 + o] * norm);
    atomicAdd(out + (size_t)NN * 16 + (size_t)d * 16 + o, hls[(size_t)s * 16 + o] * norm);
}

extern "C" void kernel_launch(void* const* d_in, const int* in_sizes, int n_in,
                              void* d_out, int out_size, void* d_ws, size_t ws_size,
                              hipStream_t stream) {
    const float* x     = (const float*)d_in[0];
    const int*   ei    = (const int*)d_in[1];
    const float* ea    = (const float*)d_in[2];
    const float* nn1_w = (const float*)d_in[3];
    const float* nn1_b = (const float*)d_in[4];
    const float* root1 = (const float*)d_in[5];
    const float* bias1 = (const float*)d_in[6];
    const float* nn2_w = (const float*)d_in[7];
    const float* nn2_b = (const float*)d_in[8];
    const float* root2 = (const float*)d_in[9];
    const float* bias2 = (const float*)d_in[10];
    const float* mu_w  = (const float*)d_in[11];
    const float* mu_b  = (const float*)d_in[12];
    const float* ls_w  = (const float*)d_in[13];
    const float* ls_b  = (const float*)d_in[14];
    float* out = (float*)d_out;

    // Workspace layout (floats). T2 aliases T1 (T1 dead after k_h1).
    float* W    = (float*)d_ws;
    float* T1   = W;                         // 3,932,160
    float* T2   = W;                         // alias
    float* agg1 = W + 3932160;               // 393,216
    float* agg2 = agg1 + 393216;             // 262,144
    int* cnt_src = (int*)(agg2 + 262144);    // 8,192
    int* cnt_dst = cnt_src + 8192;           // 8,192
    float* h1   = (float*)(cnt_dst + 8192);  // 393,216
    float* hmu  = h1 + 393216;               // 131,072
    float* hls  = hmu + 131072;              // 131,072
    float* dinv = hls + 131072;              // 8,192
    int* cursor = (int*)(dinv + 8192);       // 8,192
    int* ssrc   = cursor + 8192;             // 65,536
    int* sdst   = ssrc + 65536;              // 65,536
    float* sea  = (float*)(sdst + 65536);    // 524,288
    // total ~23.7 MB

    // Zero agg1+agg2+cnt_src+cnt_dst in one pass (contiguous, 671,744 floats).
    k_zero<<<dim3(656), dim3(256), 0, stream>>>(agg1, 167936);
    k_count<<<dim3(EE / 256), dim3(256), 0, stream>>>(ei, cnt_src, cnt_dst);
    k_T1<<<dim3(NN / 16), dim3(256), 0, stream>>>(x, nn1_w, nn1_b, root1, T1);
    k_scan<<<dim3(1), dim3(256), 0, stream>>>(cnt_src, cursor);
    k_scatter<<<dim3(EE / 256), dim3(256), 0, stream>>>(ei, ea, cursor, ssrc, sdst, sea);
    k_edge1<<<dim3((EE * 48) / 256), dim3(256), 0, stream>>>(ssrc, sdst, sea, T1, agg1);
    k_h1<<<dim3((NN * 48) / 256), dim3(256), 0, stream>>>(agg1, T1, bias1, h1);
    k_T2<<<dim3(NN / 16), dim3(256), 0, stream>>>(h1, nn2_w, nn2_b, root2, T2);
    k_edge2<<<dim3((EE * 32) / 256), dim3(256), 0, stream>>>(ssrc, sdst, sea, T2, agg2);
    k_post<<<dim3(NN / 8), dim3(256), 0, stream>>>(agg2, T2, bias2, mu_w, mu_b,
                                                   ls_w, ls_b, cnt_dst, hmu, hls, dinv, out);
    k_gcn_edge<<<dim3((EE * 16) / 256), dim3(256), 0, stream>>>(ssrc, sdst, hmu, hls, dinv, out);
}